// Round 4
// baseline (1867.081 us; speedup 1.0000x reference)
//
#include <hip/hip_runtime.h>
#include <hip/hip_fp16.h>
#include <math.h>

#define N_NODES 50000
#define N_EDGES 800000
#define DIM 64
#define N_LAYERS 5

#define POOL_REP 16

#define BROWS 128    // nodes per bucket / per layer block
#define LSTR 68      // fp32 LDS row stride (16B-aligned rows, bank-spread)
#define NB 391       // ceil(50000/128)
#define CAPB 2560    // per-bucket edge capacity (mean 2048, sigma ~45, +11 sigma)
#define BF2_BLOCKS 512
#define EPB2 ((N_EDGES + BF2_BLOCKS - 1) / BF2_BLOCKS)   // 1563 edges per bfill2 block

#define WFRAG_PER_LAYER (3 * 2 * 4 * 64 * 8)   // 12288 shorts (hi-only)
#define XP (N_NODES * DIM / 4)                  // 800000 xprep items (4 elems each)
#define WP (N_LAYERS * WFRAG_PER_LAYER)         // 61440 wprep items

typedef __attribute__((ext_vector_type(8))) short short8;
typedef __attribute__((ext_vector_type(4))) float floatx4;

__device__ inline unsigned short bf16_rne(float f) {
    unsigned int u = __float_as_uint(f);
    return (unsigned short)((u + 0x7FFFu + ((u >> 16) & 1u)) >> 16);
}
// fp8 e5m2 = top byte of fp16. Decode: 2 ops. Encode: f32->f16 RNE, then RNE on 8-bit boundary.
__device__ inline float e5m2_f32(unsigned char b) {
    return __half2float(__ushort_as_half((unsigned short)((unsigned short)b << 8)));
}
__device__ inline unsigned char f32_e5m2(float f) {
    unsigned short us = __half_as_ushort(__float2half(f));
    us = (unsigned short)(us + 0x7F + ((us >> 8) & 1));
    return (unsigned char)(us >> 8);
}
// Pack bytes {b0,b1} / {b2,b3} of a dword into half2 {b<<8, b'<<8} via v_perm_b32.
__device__ inline __half2 e5m2x2_lo(unsigned d) {
    unsigned h = __builtin_amdgcn_perm(0u, d, 0x01050004u);  // bytes [0,b0,0,b1]
    return __builtin_bit_cast(__half2, h);
}
__device__ inline __half2 e5m2x2_hi(unsigned d) {
    unsigned h = __builtin_amdgcn_perm(0u, d, 0x03070206u);  // bytes [0,b2,0,b3]
    return __builtin_bit_cast(__half2, h);
}
// decode 8 fp8 dims (uint2) -> 8 f32
__device__ inline void dec8(uint2 d, float* f) {
    float2 a = __half22float2(e5m2x2_lo(d.x));
    float2 b = __half22float2(e5m2x2_hi(d.x));
    float2 c = __half22float2(e5m2x2_lo(d.y));
    float2 e = __half22float2(e5m2x2_hi(d.y));
    f[0] = a.x; f[1] = a.y; f[2] = b.x; f[3] = b.y;
    f[4] = c.x; f[5] = c.y; f[6] = e.x; f[7] = e.y;
}

// ---------------- fused prep: x->fp8, W->bf16 frags (hi only), zero bucketCnt+pooled ----------------
__global__ __launch_bounds__(256) void prep_kernel(const float* __restrict__ x,
                                                   const float* __restrict__ W,
                                                   unsigned char* __restrict__ x8,
                                                   unsigned short* __restrict__ wfrag,
                                                   int* __restrict__ bucketCnt,
                                                   float* __restrict__ pooled) {
    int i = blockIdx.x * 256 + threadIdx.x;
    if (i < XP) {
        float4 v = ((const float4*)x)[i];
        uchar4 u;
        u.x = f32_e5m2(v.x); u.y = f32_e5m2(v.y);
        u.z = f32_e5m2(v.z); u.w = f32_e5m2(v.w);
        ((uchar4*)x8)[i] = u;
        return;
    }
    i -= XP;
    if (i < WP) {
        int t = i;
        int j    = t & 7;
        int lane = (t >> 3) & 63;
        int nt   = (t >> 9) & 3;
        int kt   = (t >> 11) & 1;
        int rest = t >> 12;
        int p    = rest % 3;
        int layer= rest / 3;
        int k = kt * 32 + (lane >> 4) * 8 + j;
        int n = nt * 16 + (lane & 15);
        float v = W[(((size_t)layer * 3 + p) * 64 + k) * 64 + n];
        wfrag[t] = bf16_rne(v);
        return;
    }
    i -= WP;
    if (i < NB) { bucketCnt[i] = 0; return; }
    i -= NB;
    if (i < N_LAYERS * POOL_REP * DIM) pooled[i] = 0.f;
}

// ---------------- bucketed edge partition (width-128 buckets) ----------------
__global__ __launch_bounds__(256) void bfill2_kernel(const int* __restrict__ src,
                                                     const int* __restrict__ dst,
                                                     int* __restrict__ bucketCnt,
                                                     int* __restrict__ ebuf) {
    __shared__ int cnt[NB];
    __shared__ int basev[NB];
    const int t = threadIdx.x;
    const int e0 = blockIdx.x * EPB2;
    for (int j = t; j < NB; j += 256) cnt[j] = 0;
    __syncthreads();
    for (int i = t; i < EPB2; i += 256) {
        int e = e0 + i;
        if (e < N_EDGES) atomicAdd(&cnt[dst[e] >> 7], 1);
    }
    __syncthreads();
    for (int j = t; j < NB; j += 256) {
        int c = cnt[j];
        basev[j] = c ? atomicAdd(&bucketCnt[j], c) : 0;
        cnt[j] = 0;   // reuse as in-block cursor
    }
    __syncthreads();
    for (int i = t; i < EPB2; i += 256) {
        int e = e0 + i;
        if (e < N_EDGES) {
            int d = dst[e];
            int b = d >> 7;
            int pos = atomicAdd(&cnt[b], 1);
            ebuf[(size_t)b * CAPB + basev[b] + pos] = ((d & 127) << 16) | src[e];
        }
    }
}

// ---------------- fused layer: bucket-local scatter-add (ds_add_f32) + MFMA MLP ----------------
__global__ __launch_bounds__(512) void layer_kernel(const unsigned char* __restrict__ h8,
                                                    const int* __restrict__ ebuf_,
                                                    const int* __restrict__ bucketCnt,
                                                    const unsigned short* __restrict__ wf,
                                                    unsigned char* __restrict__ h_out,
                                                    float* __restrict__ pooled) {  // [POOL_REP][64]
    __shared__ float acc[BROWS * LSTR];   // 34.8 KB fp32 accumulator
    __shared__ int eL[CAPB];              // 10.2 KB staged edges
    const int tid  = threadIdx.x;
    const int lane = tid & 63;
    const int w    = __builtin_amdgcn_readfirstlane(tid >> 6);   // 0..7
    const int b    = blockIdx.x;
    const int n0   = b * BROWS;
    const int cnt_b = bucketCnt[b];
    const int gd   = (tid & 7) << 3;      // this thread's 8-dim slot (also h8 byte offset)

    // ---- init: acc row = self h (eps=0 term); invalid rows -> 0. Stage edges to LDS. ----
    #pragma unroll
    for (int it = 0; it < 2; ++it) {
        int slot = tid + it * 512;        // 1024 slots = 128 rows x 8 octets
        int r = slot >> 3;
        int g8 = (slot & 7) << 3;
        int node = n0 + r;
        float f[8] = {0.f, 0.f, 0.f, 0.f, 0.f, 0.f, 0.f, 0.f};
        if (node < N_NODES) {
            uint2 d = *(const uint2*)(h8 + (((size_t)node) << 6) + g8);
            dec8(d, f);
        }
        float4 lo, hi;
        lo.x = f[0]; lo.y = f[1]; lo.z = f[2]; lo.w = f[3];
        hi.x = f[4]; hi.y = f[5]; hi.z = f[6]; hi.w = f[7];
        float* ap = &acc[r * LSTR + g8];
        *(float4*)ap = lo;
        *(float4*)(ap + 4) = hi;
    }
    const int* eb = ebuf_ + (size_t)b * CAPB;
    for (int i = tid; i < cnt_b; i += 512) eL[i] = eb[i];
    __syncthreads();

    // ---- edge-parallel scatter: 8 lanes per edge, independent loads, fire-and-forget ds_add ----
    const int tot = cnt_b << 3;
    int i = tid;
    for (; i + 512 < tot; i += 1024) {
        int e0 = eL[i >> 3];
        int e1 = eL[(i + 512) >> 3];
        uint2 d0 = *(const uint2*)(h8 + (unsigned)(((e0 & 0xFFFF) << 6) | gd));
        uint2 d1 = *(const uint2*)(h8 + (unsigned)(((e1 & 0xFFFF) << 6) | gd));
        float f0[8], f1[8];
        dec8(d0, f0);
        dec8(d1, f1);
        float* a0 = &acc[(e0 >> 16) * LSTR + gd];
        #pragma unroll
        for (int k = 0; k < 8; ++k) atomicAdd(&a0[k], f0[k]);
        float* a1 = &acc[(e1 >> 16) * LSTR + gd];
        #pragma unroll
        for (int k = 0; k < 8; ++k) atomicAdd(&a1[k], f1[k]);
    }
    if (i < tot) {
        int e0 = eL[i >> 3];
        uint2 d0 = *(const uint2*)(h8 + (unsigned)(((e0 & 0xFFFF) << 6) | gd));
        float f0[8];
        dec8(d0, f0);
        float* a0 = &acc[(e0 >> 16) * LSTR + gd];
        #pragma unroll
        for (int k = 0; k < 8; ++k) atomicAdd(&a0[k], f0[k]);
    }
    __syncthreads();

    // ---- MLP: hi-only bf16 MFMA; wave w owns rows w*16..w*16+15 (wave-private, no barriers) ----
    const int mrow = lane & 15;
    const int quad = lane >> 4;
    const int rbase = w * 16;
    const short8* Bf = (const short8*)wf;

    for (int p = 0; p < 3; ++p) {
        short8 Ahi[2];
        #pragma unroll
        for (int kt = 0; kt < 2; ++kt) {
            const float* ap = &acc[(rbase + mrow) * LSTR + kt * 32 + quad * 8];
            float4 f0 = *(const float4*)ap;
            float4 f1 = *(const float4*)(ap + 4);
            float fv[8] = {f0.x, f0.y, f0.z, f0.w, f1.x, f1.y, f1.z, f1.w};
            short8 hi;
            #pragma unroll
            for (int jj = 0; jj < 8; ++jj)
                hi[jj] = (short)bf16_rne(fv[jj]);
            Ahi[kt] = hi;
        }

        floatx4 accv[4];
        #pragma unroll
        for (int nt = 0; nt < 4; ++nt) { accv[nt][0]=0.f; accv[nt][1]=0.f; accv[nt][2]=0.f; accv[nt][3]=0.f; }

        #pragma unroll
        for (int nt = 0; nt < 4; ++nt) {
            #pragma unroll
            for (int kt = 0; kt < 2; ++kt) {
                int fbase = ((p * 2 + kt) * 4 + nt) * 64 + lane;
                short8 bhi = Bf[fbase];
                accv[nt] = __builtin_amdgcn_mfma_f32_16x16x32_bf16(Ahi[kt], bhi, accv[nt], 0, 0, 0);
            }
        }
        // relu-write back to this wave's own rows (same-wave in-order DS pipe)
        #pragma unroll
        for (int nt = 0; nt < 4; ++nt) {
            #pragma unroll
            for (int reg = 0; reg < 4; ++reg) {
                int row = rbase + quad * 4 + reg;
                acc[row * LSTR + nt * 16 + mrow] = fmaxf(accv[nt][reg], 0.f);
            }
        }
    }
    asm volatile("s_waitcnt lgkmcnt(0)" ::: "memory");

    // ---- store wave-private rows as fp8 (coalesced uchar4; guard tail bucket) ----
    #pragma unroll
    for (int it = 0; it < 4; ++it) {
        int slot = it * 64 + lane;            // 256 slots = 16 rows x 16 uchar4
        int r = rbase + (slot >> 4);
        int c = (slot & 15) << 2;
        int node = n0 + r;
        if (node < N_NODES) {
            float4 v = *(const float4*)&acc[r * LSTR + c];
            uchar4 u;
            u.x = f32_e5m2(v.x); u.y = f32_e5m2(v.y);
            u.z = f32_e5m2(v.z); u.w = f32_e5m2(v.w);
            *(uchar4*)(h_out + (size_t)node * DIM + c) = u;
        }
    }

    // ---- pool partial over this wave's 16 rows (invalid rows hold exact zeros) ----
    float s = 0.f;
    #pragma unroll
    for (int r = 0; r < 16; ++r)
        s += acc[(rbase + r) * LSTR + lane];
    atomicAdd(&pooled[(((b << 3) + w) & (POOL_REP - 1)) * DIM + lane], s);
}

__global__ void finalize_kernel(const float* __restrict__ pooled,  // [L][POOL_REP][64]
                                const float* __restrict__ Wl,
                                float* __restrict__ out) {
    int c = threadIdx.x;  // 64
    float s = 0.f;
    #pragma unroll
    for (int l = 0; l < N_LAYERS; ++l) {
        float col = 0.f;
        #pragma unroll
        for (int r = 0; r < POOL_REP; ++r)
            col += pooled[(l * POOL_REP + r) * DIM + c];
        s += col * Wl[l * DIM + c];
    }
    #pragma unroll
    for (int off = 32; off > 0; off >>= 1)
        s += __shfl_down(s, off, 64);
    if (c == 0) {
        float logit = s / (float)N_NODES;
        out[0] = 1.f / (1.f + expf(-logit));
    }
}

extern "C" void kernel_launch(void* const* d_in, const int* in_sizes, int n_in,
                              void* d_out, int out_size, void* d_ws, size_t ws_size,
                              hipStream_t stream) {
    const float* x   = (const float*)d_in[0];
    const float* W   = (const float*)d_in[1];
    const float* Wl  = (const float*)d_in[2];
    const int*   src = (const int*)d_in[3];
    const int*   dst = (const int*)d_in[4];
    float* out = (float*)d_out;

    char* ws = (char*)d_ws;
    const size_t h8Bytes = (size_t)N_NODES * DIM;                     // 3.2 MB
    unsigned char* hX = (unsigned char*)(ws);
    unsigned char* hA = (unsigned char*)(ws + h8Bytes);
    unsigned char* hB = (unsigned char*)(ws + 2 * h8Bytes);
    int*   ebuf     = (int*)(ws + 3 * h8Bytes);                       // NB*CAPB = 4.0 MB
    int*   bucketCnt= ebuf + (size_t)NB * CAPB;                       // NB
    float* pooled   = (float*)(bucketCnt + NB);                       // 5*16*64 floats
    unsigned short* wfrag = (unsigned short*)(pooled + N_LAYERS * POOL_REP * DIM);

    const int prepItems = XP + WP + NB + N_LAYERS * POOL_REP * DIM;
    prep_kernel<<<(prepItems + 255) / 256, 256, 0, stream>>>(x, W, hX, wfrag, bucketCnt, pooled);
    bfill2_kernel<<<BF2_BLOCKS, 256, 0, stream>>>(src, dst, bucketCnt, ebuf);

    const unsigned char* hcur = hX;
    unsigned char* hnext = hA;
    for (int l = 0; l < N_LAYERS; ++l) {
        layer_kernel<<<NB, 512, 0, stream>>>(
            hcur, ebuf, bucketCnt, wfrag + (size_t)l * WFRAG_PER_LAYER, hnext,
            pooled + (size_t)l * POOL_REP * DIM);
        hcur = hnext;
        hnext = (hnext == hA) ? hB : hA;
    }
    finalize_kernel<<<1, 64, 0, stream>>>(pooled, Wl, out);
}

// Round 5
// 750.660 us; speedup vs baseline: 2.4873x; 2.4873x over previous
//
#include <hip/hip_runtime.h>
#include <hip/hip_fp16.h>
#include <math.h>

#define N_NODES 50000
#define N_EDGES 800000
#define DIM 64
#define N_LAYERS 5

#define BLK 128      // two waves per block
#define ROWS 32      // 16 rows per wave
#define HSTRIDE 68   // 16B-aligned rows, bank-spread
#define POOL_REP 16

#define NB 196       // coarse buckets = ceil(N_NODES/256)
#define CAPB 5632    // fixed region per bucket (mean 4082, sigma ~64)
#define BF_BLOCKS 512
#define EPB2 ((N_EDGES + BF_BLOCKS - 1) / BF_BLOCKS)   // 1563 edges per bfill chunk

#define EBCAP 512    // per-wave LDS edge buffer (span ~Poisson(256), 16 sigma + fallback)

#define GRID_L 782   // persistent-layer grid; 782 <= worst-case residency 1024 (4/CU @ VGPR<=256)
#define NCHUNK 1563  // 32-row chunks covering 50016 rows

#define WFRAG_PER_LAYER (3 * 2 * 4 * 64 * 8)   // 12288 shorts (hi-only)
#define XP (N_NODES * DIM / 4)                  // 800000 x-conv items
#define WP (N_LAYERS * WFRAG_PER_LAYER)         // 61440 w-conv items
#define PREP_BLOCKS ((XP + WP) / 256)           // 3365 exact

typedef __attribute__((ext_vector_type(8))) short short8;
typedef __attribute__((ext_vector_type(4))) float floatx4;

__device__ inline unsigned short bf16_rne(float f) {
    unsigned int u = __float_as_uint(f);
    return (unsigned short)((u + 0x7FFFu + ((u >> 16) & 1u)) >> 16);
}
// fp8 e5m2 = top byte of fp16. Decode: 2 ops. Encode: f32->f16 RNE, then RNE on 8-bit boundary.
__device__ inline float e5m2_f32(unsigned char b) {
    return __half2float(__ushort_as_half((unsigned short)((unsigned short)b << 8)));
}
__device__ inline unsigned char f32_e5m2(float f) {
    unsigned short us = __half_as_ushort(__float2half(f));
    us = (unsigned short)(us + 0x7F + ((us >> 8) & 1));
    return (unsigned char)(us >> 8);
}
// Pack bytes {b0,b1} / {b2,b3} of a dword into half2 {b<<8, b'<<8} via v_perm_b32.
__device__ inline __half2 e5m2x2_lo(unsigned d) {
    unsigned h = __builtin_amdgcn_perm(0u, d, 0x01050004u);
    return __builtin_bit_cast(__half2, h);
}
__device__ inline __half2 e5m2x2_hi(unsigned d) {
    unsigned h = __builtin_amdgcn_perm(0u, d, 0x03070206u);
    return __builtin_bit_cast(__half2, h);
}

// ---------------- merged setup: prep (x->fp8, W->frags) + bucketed edge partition ----------------
// bucketCnt/pooled/bar are zeroed by hipMemsetAsync BEFORE this kernel (ordering-safe).
__global__ __launch_bounds__(256) void setup_kernel(const float* __restrict__ x,
                                                    const float* __restrict__ W,
                                                    const int* __restrict__ src,
                                                    const int* __restrict__ dst,
                                                    unsigned char* __restrict__ x8,
                                                    unsigned short* __restrict__ wfrag,
                                                    int* __restrict__ bucketCnt,
                                                    int* __restrict__ ebuf) {
    __shared__ int cnt[NB];
    __shared__ int basev[NB];
    int b = blockIdx.x;
    const int t = threadIdx.x;
    if (b < PREP_BLOCKS) {
        int i = b * 256 + t;
        if (i < XP) {
            float4 v = ((const float4*)x)[i];
            uchar4 u;
            u.x = f32_e5m2(v.x); u.y = f32_e5m2(v.y);
            u.z = f32_e5m2(v.z); u.w = f32_e5m2(v.w);
            ((uchar4*)x8)[i] = u;
        } else {
            int tt = i - XP;   // < WP exactly
            int j    = tt & 7;
            int lane = (tt >> 3) & 63;
            int nt   = (tt >> 9) & 3;
            int kt   = (tt >> 11) & 1;
            int rest = tt >> 12;
            int p    = rest % 3;
            int layer= rest / 3;
            int k = kt * 32 + (lane >> 4) * 8 + j;
            int n = nt * 16 + (lane & 15);
            float v = W[(((size_t)layer * 3 + p) * 64 + k) * 64 + n];
            wfrag[tt] = bf16_rne(v);
        }
        return;
    }
    // ---- bfill part: bucketed partition of one edge chunk ----
    b -= PREP_BLOCKS;
    const int e0 = b * EPB2;
    for (int j = t; j < NB; j += 256) cnt[j] = 0;
    __syncthreads();
    for (int i = t; i < EPB2; i += 256) {
        int e = e0 + i;
        if (e < N_EDGES) atomicAdd(&cnt[dst[e] >> 8], 1);
    }
    __syncthreads();
    for (int j = t; j < NB; j += 256) {
        int c = cnt[j];
        basev[j] = c ? atomicAdd(&bucketCnt[j], c) : 0;
        cnt[j] = 0;   // reuse as in-block cursor
    }
    __syncthreads();
    for (int i = t; i < EPB2; i += 256) {
        int e = e0 + i;
        if (e < N_EDGES) {
            int d = dst[e];
            int bb = d >> 8;
            int pos = atomicAdd(&cnt[bb], 1);
            ebuf[(size_t)bb * CAPB + basev[bb] + pos] = ((d & 255) << 16) | src[e];
        }
    }
}

// ---------------- CSR build: LDS-sorted, coalesced csr_src writes ----------------
__global__ __launch_bounds__(512) void bbuild_kernel(const int* __restrict__ ebuf,
                                                     const int* __restrict__ bucketCnt,
                                                     int* __restrict__ rowptr,
                                                     int* __restrict__ csr_src) {
    __shared__ int cnt[256];
    __shared__ int cur[256];
    __shared__ int wred[8];
    __shared__ int wscan[4];
    __shared__ int lds_e[CAPB];
    __shared__ unsigned short lds_s[CAPB];
    const int t = threadIdx.x;       // 0..511
    const int lane = t & 63;
    const int wv = t >> 6;           // 0..7
    const int b = blockIdx.x;

    // base = sum_{j<b} bucketCnt[j] via wave butterfly reduce
    int v = (t < b && t < NB) ? bucketCnt[t] : 0;
    #pragma unroll
    for (int off = 32; off > 0; off >>= 1) v += __shfl_xor(v, off, 64);
    if (lane == 0) wred[wv] = v;
    if (t < 256) cnt[t] = 0;
    __syncthreads();
    const int base  = wred[0] + wred[1] + wred[2] + wred[3];
    const int cnt_b = bucketCnt[b];
    const int* __restrict__ ereg = ebuf + (size_t)b * CAPB;

    for (int i = t; i < cnt_b; i += 512) {
        int e = ereg[i];
        lds_e[i] = e;
        atomicAdd(&cnt[e >> 16], 1);
    }
    __syncthreads();

    // inclusive shuffle-scan of cnt[256] by waves 0..3
    int excl = 0;
    if (t < 256) {
        int s = cnt[t];
        #pragma unroll
        for (int off = 1; off < 64; off <<= 1) {
            int u = __shfl_up(s, off, 64);
            if (lane >= off) s += u;
        }
        if (lane == 63) wscan[wv] = s;
        excl = s - cnt[t];
    }
    __syncthreads();
    if (t < 256) {
        int woff = 0;
        #pragma unroll
        for (int j = 0; j < 4; ++j) if (j < wv) woff += wscan[j];
        excl += woff;
        rowptr[b * 256 + t] = base + excl;
        cur[t] = excl;
    }
    __syncthreads();
    // scatter to LDS (ushort src ids), then coalesced global write
    for (int i = t; i < cnt_b; i += 512) {
        int e = lds_e[i];
        int pos = atomicAdd(&cur[e >> 16], 1);
        lds_s[pos] = (unsigned short)(e & 0xFFFF);
    }
    __syncthreads();
    for (int i = t; i < cnt_b; i += 512)
        csr_src[base + i] = (int)lds_s[i];
}

// ---------------- one 32-row layer chunk (R2-proven structure) ----------------
__device__ __forceinline__ void layer_chunk(const int v,
                                            const unsigned char* __restrict__ h8,
                                            const int* __restrict__ rowptr,
                                            const int* __restrict__ csr_src,
                                            const unsigned short* __restrict__ wf,
                                            unsigned char* __restrict__ h_out,
                                            float* __restrict__ pooled,
                                            float* H, int (*EB)[EBCAP]) {
    const int tid  = threadIdx.x;
    const int lane = tid & 63;
    const int w    = __builtin_amdgcn_readfirstlane(tid >> 6);
    const int n0   = v * ROWS;
    const int nw   = n0 + w * 16;
    const int o8   = (lane & 7) << 3;     // byte offset of this lane's 8 dims
    const int rg   = lane >> 3;           // row id 0..7 within octet-group

    int rpv = rowptr[nw + min(lane, 16)];
    const int e0w  = __builtin_amdgcn_readlane(rpv, 0);
    const int span = __builtin_amdgcn_readlane(rpv, 16) - e0w;

    if (span <= EBCAP) {
        for (int i = lane; i < span; i += 64)
            EB[w][i] = csr_src[e0w + i] << 6;
        asm volatile("s_waitcnt lgkmcnt(0) vmcnt(0)" ::: "memory");
        const int* eb = &EB[w][0];

        for (int g = 0; g < 2; ++g) {
            const int myrow = g * 8 + rg;
            const int e0q = __shfl(rpv, myrow, 64);
            const int deg = __shfl(rpv, myrow + 1, 64) - e0q;
            int Rm = deg;
            Rm = max(Rm, __shfl_xor(Rm, 8, 64));
            Rm = max(Rm, __shfl_xor(Rm, 16, 64));
            Rm = max(Rm, __shfl_xor(Rm, 32, 64));
            const int Rpad = (Rm + 7) & ~7;
            const int rowq = nw + myrow;
            const int rq6  = rowq << 6;
            const int ob   = e0q - e0w;

            __half2 a01 = __float2half2_rn(0.f);
            __half2 a23 = a01, a45 = a01, a67 = a01;

            for (int i = 0; i < Rpad; i += 8) {
                uint2 dv[8];
                #pragma unroll
                for (int k = 0; k < 8; ++k) {
                    int s6 = eb[ob + i + k];
                    s6 = (i + k < deg) ? s6 : rq6;
                    dv[k] = *(const uint2*)(h8 + (unsigned)(s6 | o8));
                }
                #pragma unroll
                for (int k = 0; k < 8; ++k) {
                    a01 = __hadd2(a01, e5m2x2_lo(dv[k].x));
                    a23 = __hadd2(a23, e5m2x2_hi(dv[k].x));
                    a45 = __hadd2(a45, e5m2x2_lo(dv[k].y));
                    a67 = __hadd2(a67, e5m2x2_hi(dv[k].y));
                }
            }

            uint2 sd = *(const uint2*)(h8 + (unsigned)(rq6 | o8));
            float scale = (float)(1 - (Rpad - deg));
            float2 f01 = __half22float2(a01), f23 = __half22float2(a23);
            float2 f45 = __half22float2(a45), f67 = __half22float2(a67);
            float4 r0, r1;
            r0.x = f01.x + e5m2_f32((unsigned char)(sd.x      )) * scale;
            r0.y = f01.y + e5m2_f32((unsigned char)(sd.x >>  8)) * scale;
            r0.z = f23.x + e5m2_f32((unsigned char)(sd.x >> 16)) * scale;
            r0.w = f23.y + e5m2_f32((unsigned char)(sd.x >> 24)) * scale;
            r1.x = f45.x + e5m2_f32((unsigned char)(sd.y      )) * scale;
            r1.y = f45.y + e5m2_f32((unsigned char)(sd.y >>  8)) * scale;
            r1.z = f67.x + e5m2_f32((unsigned char)(sd.y >> 16)) * scale;
            r1.w = f67.y + e5m2_f32((unsigned char)(sd.y >> 24)) * scale;
            if (rowq >= N_NODES) {
                r0.x = 0.f; r0.y = 0.f; r0.z = 0.f; r0.w = 0.f;
                r1.x = 0.f; r1.y = 0.f; r1.z = 0.f; r1.w = 0.f;
            }
            float* hp = &H[(w * 16 + myrow) * HSTRIDE + o8];
            *(float4*)hp = r0;
            *(float4*)(hp + 4) = r1;
        }
    } else {
        for (int j = 0; j < 16; ++j) {
            const int n = nw + j;
            const int e0 = __builtin_amdgcn_readlane(rpv, j);
            const int e1 = __builtin_amdgcn_readlane(rpv, j + 1);
            float acc = 0.f;
            if (n < N_NODES) {
                float self = e5m2_f32(h8[(size_t)n * DIM + lane]);
                acc = self;
                for (int base = e0; base < e1; base += 64) {
                    const int m  = min(64, e1 - base);
                    const int mr = (m + 3) & ~3;
                    int idx = (lane < m) ? csr_src[base + lane] : n;
                    acc -= (float)(mr - m) * self;
                    for (int jj = 0; jj < mr; jj += 4) {
                        int s0 = __builtin_amdgcn_readlane(idx, jj + 0);
                        int s1 = __builtin_amdgcn_readlane(idx, jj + 1);
                        int s2 = __builtin_amdgcn_readlane(idx, jj + 2);
                        int s3 = __builtin_amdgcn_readlane(idx, jj + 3);
                        float v0 = e5m2_f32(h8[(size_t)s0 * DIM + lane]);
                        float v1 = e5m2_f32(h8[(size_t)s1 * DIM + lane]);
                        float v2 = e5m2_f32(h8[(size_t)s2 * DIM + lane]);
                        float v3 = e5m2_f32(h8[(size_t)s3 * DIM + lane]);
                        acc += (v0 + v1) + (v2 + v3);
                    }
                }
            }
            H[(w * 16 + j) * HSTRIDE + lane] = acc;
        }
    }
    // wave-private: aggregation/MFMA/relu all stay in this wave's 16 H rows
    asm volatile("s_waitcnt lgkmcnt(0)" ::: "memory");

    const int mrow = lane & 15;
    const int quad = lane >> 4;
    const short8* Bf = (const short8*)wf;

    for (int p = 0; p < 3; ++p) {
        short8 Ahi[2];
        #pragma unroll
        for (int kt = 0; kt < 2; ++kt) {
            const float* ap = &H[(w * 16 + mrow) * HSTRIDE + kt * 32 + quad * 8];
            float4 f0 = *(const float4*)ap;
            float4 f1 = *(const float4*)(ap + 4);
            float fv[8] = {f0.x, f0.y, f0.z, f0.w, f1.x, f1.y, f1.z, f1.w};
            short8 hi;
            #pragma unroll
            for (int jj = 0; jj < 8; ++jj)
                hi[jj] = (short)bf16_rne(fv[jj]);
            Ahi[kt] = hi;
        }
        floatx4 acc[4];
        #pragma unroll
        for (int nt = 0; nt < 4; ++nt) { acc[nt][0]=0.f; acc[nt][1]=0.f; acc[nt][2]=0.f; acc[nt][3]=0.f; }
        #pragma unroll
        for (int nt = 0; nt < 4; ++nt) {
            #pragma unroll
            for (int kt = 0; kt < 2; ++kt) {
                int fbase = ((p * 2 + kt) * 4 + nt) * 64 + lane;
                short8 bhi = Bf[fbase];
                acc[nt] = __builtin_amdgcn_mfma_f32_16x16x32_bf16(Ahi[kt], bhi, acc[nt], 0, 0, 0);
            }
        }
        #pragma unroll
        for (int nt = 0; nt < 4; ++nt) {
            #pragma unroll
            for (int reg = 0; reg < 4; ++reg) {
                int row = w * 16 + quad * 4 + reg;
                H[row * HSTRIDE + nt * 16 + mrow] = fmaxf(acc[nt][reg], 0.f);
            }
        }
    }
    __syncthreads();   // cross-wave: store+pool read all 32 rows

    #pragma unroll
    for (int i = 0; i < 4; ++i) {
        int t4 = tid + i * BLK;
        int r  = t4 >> 4;
        int c  = (t4 & 15) << 2;
        int grow = n0 + r;
        if (grow < N_NODES) {
            float4 vv = *(const float4*)&H[r * HSTRIDE + c];
            uchar4 u;
            u.x = f32_e5m2(vv.x); u.y = f32_e5m2(vv.y);
            u.z = f32_e5m2(vv.z); u.w = f32_e5m2(vv.w);
            *(uchar4*)(h_out + (size_t)grow * DIM + c) = u;
        }
    }
    if (tid < 64) {
        float s = 0.f;
        #pragma unroll
        for (int r = 0; r < ROWS; ++r)
            s += H[r * HSTRIDE + tid];
        atomicAdd(&pooled[(v & (POOL_REP - 1)) * DIM + tid], s);
    }
}

// device-scope grid barrier: single L2 atomic counter, agent fences for cross-XCD visibility
__device__ __forceinline__ void gbar(int* bar, int gen) {
    __syncthreads();
    if (threadIdx.x == 0) {
        __threadfence();   // release: write back dirty lines
        __hip_atomic_fetch_add(bar, 1, __ATOMIC_ACQ_REL, __HIP_MEMORY_SCOPE_AGENT);
        const int tgt = GRID_L * (gen + 1);
        while (__hip_atomic_load(bar, __ATOMIC_ACQUIRE, __HIP_MEMORY_SCOPE_AGENT) < tgt)
            __builtin_amdgcn_s_sleep(2);
    }
    __syncthreads();
    __threadfence();       // acquire: invalidate stale L1/L2 lines before next layer's reads
}

// ---------------- persistent fused 5-layer kernel (782 co-resident blocks by construction) ----------------
__global__ __launch_bounds__(BLK, 2) void gin_layers(const unsigned char* __restrict__ hX,
                                                     unsigned char* __restrict__ hA,
                                                     unsigned char* __restrict__ hB,
                                                     const int* __restrict__ rowptr,
                                                     const int* __restrict__ csr_src,
                                                     const unsigned short* __restrict__ wfrag,
                                                     float* __restrict__ pooled,
                                                     int* __restrict__ bar) {
    __shared__ float H[ROWS * HSTRIDE];   // 8.7 KB
    __shared__ int EB[2][EBCAP];          // 4 KB
    const int b = blockIdx.x;

    for (int l = 0; l < N_LAYERS; ++l) {
        const unsigned char* hc = (l == 0) ? hX : ((l & 1) ? hA : hB);
        unsigned char* hn = (l & 1) ? hB : hA;
        const unsigned short* wf = wfrag + (size_t)l * WFRAG_PER_LAYER;
        float* pl = pooled + (size_t)l * POOL_REP * DIM;

        layer_chunk(b, hc, rowptr, csr_src, wf, hn, pl, H, EB);
        __syncthreads();                       // H reuse WAR across chunks
        if (b + GRID_L < NCHUNK)
            layer_chunk(b + GRID_L, hc, rowptr, csr_src, wf, hn, pl, H, EB);

        if (l < N_LAYERS - 1) gbar(bar, l);    // cross-layer global sync
    }
}

__global__ void finalize_kernel(const float* __restrict__ pooled,  // [L][POOL_REP][64]
                                const float* __restrict__ Wl,
                                float* __restrict__ out) {
    int c = threadIdx.x;  // 64
    float s = 0.f;
    #pragma unroll
    for (int l = 0; l < N_LAYERS; ++l) {
        float col = 0.f;
        #pragma unroll
        for (int r = 0; r < POOL_REP; ++r)
            col += pooled[(l * POOL_REP + r) * DIM + c];
        s += col * Wl[l * DIM + c];
    }
    #pragma unroll
    for (int off = 32; off > 0; off >>= 1)
        s += __shfl_down(s, off, 64);
    if (c == 0) {
        float logit = s / (float)N_NODES;
        out[0] = 1.f / (1.f + expf(-logit));
    }
}

extern "C" void kernel_launch(void* const* d_in, const int* in_sizes, int n_in,
                              void* d_out, int out_size, void* d_ws, size_t ws_size,
                              hipStream_t stream) {
    const float* x   = (const float*)d_in[0];
    const float* W   = (const float*)d_in[1];
    const float* Wl  = (const float*)d_in[2];
    const int*   src = (const int*)d_in[3];
    const int*   dst = (const int*)d_in[4];
    float* out = (float*)d_out;

    char* ws = (char*)d_ws;
    const size_t h8Bytes = (size_t)N_NODES * DIM;                     // 3.2 MB
    unsigned char* hX = (unsigned char*)(ws);
    unsigned char* hA = (unsigned char*)(ws + h8Bytes);
    unsigned char* hB = (unsigned char*)(ws + 2 * h8Bytes);
    int*   csr_src  = (int*)(ws + 3 * h8Bytes);                       // 3.2 MB
    int*   ebuf     = csr_src + N_EDGES;                              // NB*CAPB
    int*   rowptr   = ebuf + (size_t)NB * CAPB;                       // 50176 ints
    int*   bucketCnt= rowptr + NB * 256;                              // 256 ints (padded)
    int*   bar      = bucketCnt + 256;                                // 64 ints (padded)
    float* pooled   = (float*)(bar + 64);                             // 5*16*64 floats
    unsigned short* wfrag = (unsigned short*)(pooled + N_LAYERS * POOL_REP * DIM);

    // zero bucketCnt + bar + pooled in one stream-ordered memset (before any atomics)
    hipMemsetAsync(bucketCnt, 0, (256 + 64 + N_LAYERS * POOL_REP * DIM) * sizeof(int), stream);

    setup_kernel<<<PREP_BLOCKS + BF_BLOCKS, 256, 0, stream>>>(x, W, src, dst, hX, wfrag, bucketCnt, ebuf);
    bbuild_kernel<<<NB, 512, 0, stream>>>(ebuf, bucketCnt, rowptr, csr_src);
    gin_layers<<<GRID_L, BLK, 0, stream>>>(hX, hA, hB, rowptr, csr_src, wfrag, pooled, bar);
    finalize_kernel<<<1, 64, 0, stream>>>(pooled, Wl, out);
}

// Round 6
// 181.890 us; speedup vs baseline: 10.2649x; 4.1270x over previous
//
#include <hip/hip_runtime.h>
#include <hip/hip_fp16.h>
#include <math.h>

#define N_NODES 50000
#define N_EDGES 800000
#define DIM 64
#define N_LAYERS 5

#define BLK 128      // two waves per block
#define ROWS 32      // 16 rows per wave
#define HSTRIDE 68   // 16B-aligned rows for ds_read_b128
#define POOL_REP 16

#define NB 196       // coarse buckets = ceil(N_NODES/256)
#define CAPB 5632    // fixed region per bucket (mean 4082, sigma ~64)
#define BF_BLOCKS 512
#define EPB2 ((N_EDGES + BF_BLOCKS - 1) / BF_BLOCKS)   // 1563 edges per bfill chunk

#define EBCAP 512    // per-wave LDS edge buffer (span ~Poisson(256), 16 sigma + fallback)

#define WFRAG_PER_LAYER (3 * 2 * 4 * 64 * 8)   // 12288 shorts (hi-only)
#define XP (N_NODES * DIM / 4)                  // 800000 x-conv items
#define WP (N_LAYERS * WFRAG_PER_LAYER)         // 61440 w-conv items
#define PREP_BLOCKS ((XP + WP) / 256)           // 3365 exact

typedef __attribute__((ext_vector_type(8))) short short8;
typedef __attribute__((ext_vector_type(4))) float floatx4;

__device__ inline unsigned short bf16_rne(float f) {
    unsigned int u = __float_as_uint(f);
    return (unsigned short)((u + 0x7FFFu + ((u >> 16) & 1u)) >> 16);
}
// fp8 e5m2 = top byte of fp16. Decode: 2 ops. Encode: f32->f16 RNE, then RNE on 8-bit boundary.
__device__ inline float e5m2_f32(unsigned char b) {
    return __half2float(__ushort_as_half((unsigned short)((unsigned short)b << 8)));
}
__device__ inline unsigned char f32_e5m2(float f) {
    unsigned short us = __half_as_ushort(__float2half(f));
    us = (unsigned short)(us + 0x7F + ((us >> 8) & 1));
    return (unsigned char)(us >> 8);
}
// Pack bytes {b0,b1} / {b2,b3} of a dword into half2 {b<<8, b'<<8} via v_perm_b32.
__device__ inline __half2 e5m2x2_lo(unsigned d) {
    unsigned h = __builtin_amdgcn_perm(0u, d, 0x01050004u);  // bytes [0,b0,0,b1]
    return __builtin_bit_cast(__half2, h);
}
__device__ inline __half2 e5m2x2_hi(unsigned d) {
    unsigned h = __builtin_amdgcn_perm(0u, d, 0x03070206u);  // bytes [0,b2,0,b3]
    return __builtin_bit_cast(__half2, h);
}

// ---------------- merged setup: prep (x->fp8, W->frags, zero pooled) + bucketed edge partition ----
// bucketCnt is zeroed by hipMemsetAsync BEFORE this kernel (cross-block ordering safe).
__global__ __launch_bounds__(256) void setup_kernel(const float* __restrict__ x,
                                                    const float* __restrict__ W,
                                                    const int* __restrict__ src,
                                                    const int* __restrict__ dst,
                                                    unsigned char* __restrict__ x8,
                                                    unsigned short* __restrict__ wfrag,
                                                    int* __restrict__ bucketCnt,
                                                    int* __restrict__ ebuf) {
    __shared__ int cnt[NB];
    __shared__ int basev[NB];
    int b = blockIdx.x;
    const int t = threadIdx.x;
    if (b < PREP_BLOCKS) {
        int i = b * 256 + t;
        if (i < XP) {
            float4 v = ((const float4*)x)[i];
            uchar4 u;
            u.x = f32_e5m2(v.x); u.y = f32_e5m2(v.y);
            u.z = f32_e5m2(v.z); u.w = f32_e5m2(v.w);
            ((uchar4*)x8)[i] = u;
        } else {
            int tt = i - XP;   // < WP exactly
            int j    = tt & 7;
            int lane = (tt >> 3) & 63;
            int nt   = (tt >> 9) & 3;
            int kt   = (tt >> 11) & 1;
            int rest = tt >> 12;
            int p    = rest % 3;
            int layer= rest / 3;
            int k = kt * 32 + (lane >> 4) * 8 + j;
            int n = nt * 16 + (lane & 15);
            float v = W[(((size_t)layer * 3 + p) * 64 + k) * 64 + n];
            wfrag[tt] = bf16_rne(v);
        }
        return;
    }
    // ---- bfill part: bucketed partition of one edge chunk ----
    b -= PREP_BLOCKS;
    const int e0 = b * EPB2;
    for (int j = t; j < NB; j += 256) cnt[j] = 0;
    __syncthreads();
    for (int i = t; i < EPB2; i += 256) {
        int e = e0 + i;
        if (e < N_EDGES) atomicAdd(&cnt[dst[e] >> 8], 1);
    }
    __syncthreads();
    for (int j = t; j < NB; j += 256) {
        int c = cnt[j];
        basev[j] = c ? atomicAdd(&bucketCnt[j], c) : 0;
        cnt[j] = 0;   // reuse as in-block cursor
    }
    __syncthreads();
    for (int i = t; i < EPB2; i += 256) {
        int e = e0 + i;
        if (e < N_EDGES) {
            int d = dst[e];
            int bb = d >> 8;
            int pos = atomicAdd(&cnt[bb], 1);
            ebuf[(size_t)bb * CAPB + basev[bb] + pos] = ((d & 255) << 16) | src[e];
        }
    }
}

// ---------------- CSR build: 8 waves, shuffle-scan, LDS-sorted coalesced csr_src writes ----------------
__global__ __launch_bounds__(512) void bbuild_kernel(const int* __restrict__ ebuf,
                                                     const int* __restrict__ bucketCnt,
                                                     int* __restrict__ rowptr,
                                                     int* __restrict__ csr_src) {
    __shared__ int cnt[256];
    __shared__ int cur[256];
    __shared__ int wred[8];
    __shared__ int wscan[4];
    __shared__ int lds_e[CAPB];
    __shared__ unsigned short lds_s[CAPB];
    const int t = threadIdx.x;       // 0..511
    const int lane = t & 63;
    const int wv = t >> 6;           // 0..7
    const int b = blockIdx.x;

    // base = sum_{j<b} bucketCnt[j] via wave butterfly reduce
    int v = (t < b && t < NB) ? bucketCnt[t] : 0;
    #pragma unroll
    for (int off = 32; off > 0; off >>= 1) v += __shfl_xor(v, off, 64);
    if (lane == 0) wred[wv] = v;
    if (t < 256) cnt[t] = 0;
    __syncthreads();
    const int base  = wred[0] + wred[1] + wred[2] + wred[3];
    const int cnt_b = bucketCnt[b];
    const int* __restrict__ ereg = ebuf + (size_t)b * CAPB;

    for (int i = t; i < cnt_b; i += 512) {
        int e = ereg[i];
        lds_e[i] = e;
        atomicAdd(&cnt[e >> 16], 1);
    }
    __syncthreads();

    // inclusive shuffle-scan of cnt[256] by waves 0..3
    int excl = 0;
    if (t < 256) {
        int s = cnt[t];
        #pragma unroll
        for (int off = 1; off < 64; off <<= 1) {
            int u = __shfl_up(s, off, 64);
            if (lane >= off) s += u;
        }
        if (lane == 63) wscan[wv] = s;
        excl = s - cnt[t];
    }
    __syncthreads();
    if (t < 256) {
        int woff = 0;
        #pragma unroll
        for (int j = 0; j < 4; ++j) if (j < wv) woff += wscan[j];
        excl += woff;
        rowptr[b * 256 + t] = base + excl;
        cur[t] = excl;
    }
    __syncthreads();
    // scatter to LDS (ushort src ids), then coalesced global write
    for (int i = t; i < cnt_b; i += 512) {
        int e = lds_e[i];
        int pos = atomicAdd(&cur[e >> 16], 1);
        lds_s[pos] = (unsigned short)(e & 0xFFFF);
    }
    __syncthreads();
    for (int i = t; i < cnt_b; i += 512)
        csr_src[base + i] = (int)lds_s[i];
}

// ---------------- fused layer (R2-measured-best structure, unchanged) ----------------
__global__ __launch_bounds__(BLK) void layer_kernel(const unsigned char* __restrict__ h8,
                                                    const int* __restrict__ rowptr,
                                                    const int* __restrict__ csr_src,
                                                    const unsigned short* __restrict__ wf,
                                                    unsigned char* __restrict__ h_out,
                                                    float* __restrict__ pooled) {  // [POOL_REP][64]
    __shared__ float H[ROWS * HSTRIDE];   // 8.7 KB
    __shared__ int EB[2][EBCAP];          // 4 KB: per-wave staged edge span (pre-shifted <<6)
    const int tid  = threadIdx.x;
    const int lane = tid & 63;
    const int w    = __builtin_amdgcn_readfirstlane(tid >> 6);
    const int n0   = blockIdx.x * ROWS;
    const int nw   = n0 + w * 16;
    const int o8   = (lane & 7) << 3;     // byte offset of this lane's 8 dims
    const int rg   = lane >> 3;           // row id 0..7 within octet-group

    int rpv = rowptr[nw + min(lane, 16)];
    const int e0w  = __builtin_amdgcn_readlane(rpv, 0);
    const int span = __builtin_amdgcn_readlane(rpv, 16) - e0w;

    if (span <= EBCAP) {
        // stage wave's contiguous csr span into LDS, pre-shifted into byte offsets
        for (int i = lane; i < span; i += 64)
            EB[w][i] = csr_src[e0w + i] << 6;
        asm volatile("s_waitcnt lgkmcnt(0)" ::: "memory");
        const int* eb = &EB[w][0];

        // 2 groups of 8 rows; octet rg owns row 8g+rg; lane holds 8 dims at byte offset o8
        for (int g = 0; g < 2; ++g) {
            const int myrow = g * 8 + rg;
            const int e0q = __shfl(rpv, myrow, 64);
            const int deg = __shfl(rpv, myrow + 1, 64) - e0q;
            int Rm = deg;
            Rm = max(Rm, __shfl_xor(Rm, 8, 64));
            Rm = max(Rm, __shfl_xor(Rm, 16, 64));
            Rm = max(Rm, __shfl_xor(Rm, 32, 64));   // max over the 8 rows -> wave-uniform
            const int Rpad = (Rm + 7) & ~7;
            const int rowq = nw + myrow;
            const int rq6  = rowq << 6;
            const int ob   = e0q - e0w;

            __half2 a01 = __float2half2_rn(0.f);
            __half2 a23 = a01, a45 = a01, a67 = a01;

            for (int i = 0; i < Rpad; i += 8) {
                uint2 dv[8];
                #pragma unroll
                for (int k = 0; k < 8; ++k) {
                    int s6 = eb[ob + i + k];           // overreads are pad slots, replaced below
                    s6 = (i + k < deg) ? s6 : rq6;
                    dv[k] = *(const uint2*)(h8 + (unsigned)(s6 | o8));
                }
                #pragma unroll
                for (int k = 0; k < 8; ++k) {
                    a01 = __hadd2(a01, e5m2x2_lo(dv[k].x));
                    a23 = __hadd2(a23, e5m2x2_hi(dv[k].x));
                    a45 = __hadd2(a45, e5m2x2_lo(dv[k].y));
                    a67 = __hadd2(a67, e5m2x2_hi(dv[k].y));
                }
            }

            // self + exact pad-cancellation (pads added self Rpad-deg times)
            uint2 sd = *(const uint2*)(h8 + (unsigned)(rq6 | o8));
            float scale = (float)(1 - (Rpad - deg));
            float2 f01 = __half22float2(a01), f23 = __half22float2(a23);
            float2 f45 = __half22float2(a45), f67 = __half22float2(a67);
            float4 r0, r1;
            r0.x = f01.x + e5m2_f32((unsigned char)(sd.x      )) * scale;
            r0.y = f01.y + e5m2_f32((unsigned char)(sd.x >>  8)) * scale;
            r0.z = f23.x + e5m2_f32((unsigned char)(sd.x >> 16)) * scale;
            r0.w = f23.y + e5m2_f32((unsigned char)(sd.x >> 24)) * scale;
            r1.x = f45.x + e5m2_f32((unsigned char)(sd.y      )) * scale;
            r1.y = f45.y + e5m2_f32((unsigned char)(sd.y >>  8)) * scale;
            r1.z = f67.x + e5m2_f32((unsigned char)(sd.y >> 16)) * scale;
            r1.w = f67.y + e5m2_f32((unsigned char)(sd.y >> 24)) * scale;
            if (rowq >= N_NODES) {
                r0.x = 0.f; r0.y = 0.f; r0.z = 0.f; r0.w = 0.f;
                r1.x = 0.f; r1.y = 0.f; r1.z = 0.f; r1.w = 0.f;
            }
            float* hp = &H[(w * 16 + myrow) * HSTRIDE + o8];
            *(float4*)hp = r0;
            *(float4*)(hp + 4) = r1;
        }
    } else {
        // rare fallback (span > EBCAP): chunked 64-lane byte gather, any degree
        for (int j = 0; j < 16; ++j) {
            const int n = nw + j;
            const int e0 = __builtin_amdgcn_readlane(rpv, j);
            const int e1 = __builtin_amdgcn_readlane(rpv, j + 1);
            float acc = 0.f;
            if (n < N_NODES) {
                float self = e5m2_f32(h8[(size_t)n * DIM + lane]);
                acc = self;
                for (int base = e0; base < e1; base += 64) {
                    const int m  = min(64, e1 - base);
                    const int mr = (m + 3) & ~3;
                    int idx = (lane < m) ? csr_src[base + lane] : n;
                    acc -= (float)(mr - m) * self;
                    for (int jj = 0; jj < mr; jj += 4) {
                        int s0 = __builtin_amdgcn_readlane(idx, jj + 0);
                        int s1 = __builtin_amdgcn_readlane(idx, jj + 1);
                        int s2 = __builtin_amdgcn_readlane(idx, jj + 2);
                        int s3 = __builtin_amdgcn_readlane(idx, jj + 3);
                        float v0 = e5m2_f32(h8[(size_t)s0 * DIM + lane]);
                        float v1 = e5m2_f32(h8[(size_t)s1 * DIM + lane]);
                        float v2 = e5m2_f32(h8[(size_t)s2 * DIM + lane]);
                        float v3 = e5m2_f32(h8[(size_t)s3 * DIM + lane]);
                        acc += (v0 + v1) + (v2 + v3);
                    }
                }
            }
            H[(w * 16 + j) * HSTRIDE + lane] = acc;
        }
    }
    // no __syncthreads: aggregation, MFMA A/outputs, relu writes all stay within
    // this wave's 16 H rows; per-wave DS-pipe ordering guarantees RAW/WAR.
    asm volatile("s_waitcnt lgkmcnt(0)" ::: "memory");

    // ---- MLP: hi-only bf16 MFMA (wave-private in H; zero inter-stage barriers) ----
    const int mrow = lane & 15;
    const int quad = lane >> 4;
    const short8* Bf = (const short8*)wf;

    for (int p = 0; p < 3; ++p) {
        short8 Ahi[2];
        #pragma unroll
        for (int kt = 0; kt < 2; ++kt) {
            const float* ap = &H[(w * 16 + mrow) * HSTRIDE + kt * 32 + quad * 8];
            float4 f0 = *(const float4*)ap;
            float4 f1 = *(const float4*)(ap + 4);
            float fv[8] = {f0.x, f0.y, f0.z, f0.w, f1.x, f1.y, f1.z, f1.w};
            short8 hi;
            #pragma unroll
            for (int jj = 0; jj < 8; ++jj)
                hi[jj] = (short)bf16_rne(fv[jj]);
            Ahi[kt] = hi;
        }

        floatx4 acc[4];
        #pragma unroll
        for (int nt = 0; nt < 4; ++nt) { acc[nt][0]=0.f; acc[nt][1]=0.f; acc[nt][2]=0.f; acc[nt][3]=0.f; }

        #pragma unroll
        for (int nt = 0; nt < 4; ++nt) {
            #pragma unroll
            for (int kt = 0; kt < 2; ++kt) {
                int fbase = ((p * 2 + kt) * 4 + nt) * 64 + lane;
                short8 bhi = Bf[fbase];
                acc[nt] = __builtin_amdgcn_mfma_f32_16x16x32_bf16(Ahi[kt], bhi, acc[nt], 0, 0, 0);
            }
        }
        // relu-write back (same-wave RAW ordered by in-order DS pipe)
        #pragma unroll
        for (int nt = 0; nt < 4; ++nt) {
            #pragma unroll
            for (int reg = 0; reg < 4; ++reg) {
                int row = w * 16 + quad * 4 + reg;
                H[row * HSTRIDE + nt * 16 + mrow] = fmaxf(acc[nt][reg], 0.f);
            }
        }
    }
    __syncthreads();   // the ONE cross-wave barrier: store+pool read all 32 rows

    // ---- store h as fp8 e5m2 for next layer (coalesced uchar4, guarded tail) ----
    #pragma unroll
    for (int i = 0; i < 4; ++i) {
        int t4 = tid + i * BLK;
        int r  = t4 >> 4;
        int c  = (t4 & 15) << 2;
        int grow = n0 + r;
        if (grow < N_NODES) {
            float4 v = *(const float4*)&H[r * HSTRIDE + c];
            uchar4 u;
            u.x = f32_e5m2(v.x); u.y = f32_e5m2(v.y);
            u.z = f32_e5m2(v.z); u.w = f32_e5m2(v.w);
            *(uchar4*)(h_out + (size_t)grow * DIM + c) = u;
        }
    }

    // ---- pool partial (fp32 H; invalid rows hold exact zeros) ----
    if (tid < 64) {
        float s = 0.f;
        #pragma unroll
        for (int r = 0; r < ROWS; ++r)
            s += H[r * HSTRIDE + tid];
        atomicAdd(&pooled[(blockIdx.x & (POOL_REP - 1)) * DIM + tid], s);
    }
}

__global__ void finalize_kernel(const float* __restrict__ pooled,  // [L][POOL_REP][64]
                                const float* __restrict__ Wl,
                                float* __restrict__ out) {
    int c = threadIdx.x;  // 64
    float s = 0.f;
    #pragma unroll
    for (int l = 0; l < N_LAYERS; ++l) {
        float col = 0.f;
        #pragma unroll
        for (int r = 0; r < POOL_REP; ++r)
            col += pooled[(l * POOL_REP + r) * DIM + c];
        s += col * Wl[l * DIM + c];
    }
    #pragma unroll
    for (int off = 32; off > 0; off >>= 1)
        s += __shfl_down(s, off, 64);
    if (c == 0) {
        float logit = s / (float)N_NODES;
        out[0] = 1.f / (1.f + expf(-logit));
    }
}

extern "C" void kernel_launch(void* const* d_in, const int* in_sizes, int n_in,
                              void* d_out, int out_size, void* d_ws, size_t ws_size,
                              hipStream_t stream) {
    const float* x   = (const float*)d_in[0];
    const float* W   = (const float*)d_in[1];
    const float* Wl  = (const float*)d_in[2];
    const int*   src = (const int*)d_in[3];
    const int*   dst = (const int*)d_in[4];
    float* out = (float*)d_out;

    char* ws = (char*)d_ws;
    const size_t h8Bytes = (size_t)N_NODES * DIM;                     // 3.2 MB
    unsigned char* hX = (unsigned char*)(ws);
    unsigned char* hA = (unsigned char*)(ws + h8Bytes);
    unsigned char* hB = (unsigned char*)(ws + 2 * h8Bytes);
    int*   csr_src  = (int*)(ws + 3 * h8Bytes);                       // 3.2 MB
    int*   ebuf     = csr_src + N_EDGES;                              // NB*CAPB
    int*   rowptr   = ebuf + (size_t)NB * CAPB;                       // 50176 ints
    int*   bucketCnt= rowptr + NB * 256;                              // 256 ints (padded)
    float* pooled   = (float*)(bucketCnt + 256);                      // 5*16*64 floats
    unsigned short* wfrag = (unsigned short*)(pooled + N_LAYERS * POOL_REP * DIM);

    // zero bucketCnt + pooled in one tiny stream-ordered memset (before any atomics)
    hipMemsetAsync(bucketCnt, 0, (256 + N_LAYERS * POOL_REP * DIM) * sizeof(int), stream);

    setup_kernel<<<PREP_BLOCKS + BF_BLOCKS, 256, 0, stream>>>(x, W, src, dst, hX, wfrag, bucketCnt, ebuf);
    bbuild_kernel<<<NB, 512, 0, stream>>>(ebuf, bucketCnt, rowptr, csr_src);

    const unsigned char* hcur = hX;
    unsigned char* hnext = hA;
    const int grid = (N_NODES + ROWS - 1) / ROWS;   // 1563
    for (int l = 0; l < N_LAYERS; ++l) {
        layer_kernel<<<grid, BLK, 0, stream>>>(
            hcur, rowptr, csr_src, wfrag + (size_t)l * WFRAG_PER_LAYER, hnext,
            pooled + (size_t)l * POOL_REP * DIM);
        hcur = hnext;
        hnext = (hnext == hA) ? hB : hA;
    }
    finalize_kernel<<<1, 64, 0, stream>>>(pooled, Wl, out);
}